// Round 3
// baseline (12287.357 us; speedup 1.0000x reference)
//
#include <hip/hip_runtime.h>
#include <hip/hip_bf16.h>

// VQ-VAE forward. fp32 compute, bf16 storage for large intermediates.
// Batch processed in chunks of C images (C chosen at launch from ws_size):
//   per chunk: conv1 -> a1c -> conv2 -> a2c -> conv3+VQ -> ec (fp32)
//              dec1 -> d1c -> dec2 -> d2c -> dec3+MSE (fused loss)
// Workspace per chunk: 256 + C*6,553,600 bytes (C=64 -> 400 MiB, C=8 -> 52 MiB).
// Losses accumulate across chunks via atomics; outputs identical for any C.
// Outputs: [1.25*vq_mse, recon_mse, recon_mse]

typedef __hip_bfloat16 bf16;

__device__ __forceinline__ float ld(const bf16* p, long i) { return __bfloat162float(p[i]); }

// ---------------- zero accumulators ----------------
__global__ void zero_k(float* __restrict__ acc) {
    acc[threadIdx.x] = 0.f;
}

// ---------------- conv1: 3->32, s2, ReLU ----------------
__global__ __launch_bounds__(256) void conv1_k(const float* __restrict__ x,
        const float* __restrict__ w, const float* __restrict__ bias,
        bf16* __restrict__ out) {
    const int bco = blockIdx.y;            // b*32 + co  (b = chunk-local image)
    const int b = bco >> 5, co = bco & 31;
    const int tid = threadIdx.x;
    __shared__ float ws[27];
    if (tid < 27) ws[tid] = w[co * 27 + tid];
    __syncthreads();
    const int pix = blockIdx.x * 256 + tid;      // 128*128 = 16384, gridDim.x=64
    const int ow = pix & 127, oh = pix >> 7;
    const float* xb = x + (long)b * 3 * 256 * 256;
    float acc = bias[co];
    #pragma unroll
    for (int ci = 0; ci < 3; ++ci) {
        #pragma unroll
        for (int kh = 0; kh < 3; ++kh) {
            int ih = oh * 2 + kh - 1;
            if ((unsigned)ih >= 256u) continue;
            #pragma unroll
            for (int kw = 0; kw < 3; ++kw) {
                int iw = ow * 2 + kw - 1;
                if ((unsigned)iw >= 256u) continue;
                acc += xb[(ci * 256 + ih) * 256 + iw] * ws[(ci * 3 + kh) * 3 + kw];
            }
        }
    }
    out[((long)(b * 32 + co) * 128 + oh) * 128 + ow] = __float2bfloat16(fmaxf(acc, 0.f));
}

// ---------------- conv2: 32->64, s2, ReLU ----------------
__global__ __launch_bounds__(256) void conv2_k(const bf16* __restrict__ in,
        const float* __restrict__ w, const float* __restrict__ bias,
        bf16* __restrict__ out) {
    const int bco = blockIdx.y;            // b*64 + co
    const int b = bco >> 6, co = bco & 63;
    const int tid = threadIdx.x;
    __shared__ float ws[288];
    for (int i = tid; i < 288; i += 256) ws[i] = w[co * 288 + i];
    __syncthreads();
    const int pix = blockIdx.x * 256 + tid;      // 64*64 = 4096, gridDim.x=16
    const int ow = pix & 63, oh = pix >> 6;
    const bf16* ib = in + (long)b * 32 * 128 * 128;
    float acc = bias[co];
    for (int ci = 0; ci < 32; ++ci) {
        const bf16* ic = ib + ci * 128 * 128;
        #pragma unroll
        for (int kh = 0; kh < 3; ++kh) {
            int ih = oh * 2 + kh - 1;
            if ((unsigned)ih >= 128u) continue;
            #pragma unroll
            for (int kw = 0; kw < 3; ++kw) {
                int iw = ow * 2 + kw - 1;
                if ((unsigned)iw >= 128u) continue;
                acc += ld(ic, ih * 128 + iw) * ws[(ci * 3 + kh) * 3 + kw];
            }
        }
    }
    out[((long)(b * 64 + co) * 64 + oh) * 64 + ow] = __float2bfloat16(fmaxf(acc, 0.f));
}

// ---------------- conv3 (1x1, 64->16) + VQ + loss ----------------
__global__ __launch_bounds__(256) void conv3_vq_k(const bf16* __restrict__ a2,
        const float* __restrict__ w3, const float* __restrict__ b3,
        const float* __restrict__ cb, float* __restrict__ e,
        float* __restrict__ acc) {
    __shared__ float lw[16 * 64];
    __shared__ float lb[16];
    __shared__ float lcb[512 * 16];
    __shared__ float lcn[512];
    __shared__ float red[4];
    const int tid = threadIdx.x;
    for (int i = tid; i < 1024; i += 256) lw[i] = w3[i];
    if (tid < 16) lb[tid] = b3[tid];
    for (int i = tid; i < 8192; i += 256) lcb[i] = cb[i];
    __syncthreads();
    for (int k = tid; k < 512; k += 256) {
        float s = 0.f;
        #pragma unroll
        for (int d = 0; d < 16; ++d) { float v = lcb[k * 16 + d]; s += v * v; }
        lcn[k] = s;
    }
    __syncthreads();
    const int pix = blockIdx.x * 256 + tid;      // C*4096 pixels total
    const int xw = pix & 63, yh = (pix >> 6) & 63, b = pix >> 12;
    const bf16* ib = a2 + (long)b * 262144 + yh * 64 + xw;   // ci stride 4096
    float z[16];
    #pragma unroll
    for (int d = 0; d < 16; ++d) z[d] = lb[d];
    for (int ci = 0; ci < 64; ++ci) {
        float v = ld(ib, ci * 4096);
        #pragma unroll
        for (int d = 0; d < 16; ++d) z[d] += v * lw[d * 64 + ci];
    }
    // argmin_k ||c_k||^2 - 2 z.c_k  (||z||^2 constant per pixel)
    float best = 1e30f; int bi = 0;
    for (int k = 0; k < 512; ++k) {
        float dot = 0.f;
        #pragma unroll
        for (int d = 0; d < 16; ++d) dot += z[d] * lcb[k * 16 + d];
        float dist = lcn[k] - 2.f * dot;
        if (dist < best) { best = dist; bi = k; }
    }
    float lsum = 0.f;
    #pragma unroll
    for (int d = 0; d < 16; ++d) {
        float q = lcb[bi * 16 + d];
        float df = q - z[d];
        lsum += df * df;
        e[(long)b * 65536 + d * 4096 + yh * 64 + xw] = q;
    }
    for (int off = 32; off > 0; off >>= 1) lsum += __shfl_down(lsum, off, 64);
    if ((tid & 63) == 0) red[tid >> 6] = lsum;
    __syncthreads();
    if (tid == 0) atomicAdd(&acc[0], red[0] + red[1] + red[2] + red[3]);
}

// ---------------- dec1: convT 16->64, s2 p1 op1, ReLU ----------------
__global__ __launch_bounds__(256) void dec1_k(const float* __restrict__ e,
        const float* __restrict__ w, const float* __restrict__ bias,
        bf16* __restrict__ out) {
    const int bco = blockIdx.y;            // b*64 + co
    const int b = bco >> 6, co = bco & 63;
    const int tid = threadIdx.x;
    __shared__ float ws[16 * 9];
    for (int i = tid; i < 144; i += 256) {
        int ci = i / 9, kk = i % 9;
        ws[i] = w[(ci * 64 + co) * 9 + kk];
    }
    __syncthreads();
    const int pix = blockIdx.x * 256 + tid;      // 128*128, gridDim.x=64
    const int ow = pix & 127, oh = pix >> 7;
    const float* ib = e + (long)b * 16 * 4096;
    float acc = bias[co];
    #pragma unroll
    for (int kh = 0; kh < 3; ++kh) {
        int t = oh + 1 - kh;
        if (t & 1) continue;
        int ih = t >> 1;
        if ((unsigned)ih >= 64u) continue;
        #pragma unroll
        for (int kw = 0; kw < 3; ++kw) {
            int u = ow + 1 - kw;
            if (u & 1) continue;
            int iw = u >> 1;
            if ((unsigned)iw >= 64u) continue;
            #pragma unroll
            for (int ci = 0; ci < 16; ++ci)
                acc += ib[(ci * 64 + ih) * 64 + iw] * ws[ci * 9 + kh * 3 + kw];
        }
    }
    out[((long)(b * 64 + co) * 128 + oh) * 128 + ow] = __float2bfloat16(fmaxf(acc, 0.f));
}

// ---------------- dec2: convT 64->32, s2 p1 op1, ReLU ----------------
__global__ __launch_bounds__(256) void dec2_k(const bf16* __restrict__ in,
        const float* __restrict__ w, const float* __restrict__ bias,
        bf16* __restrict__ out) {
    const int bco = blockIdx.y;            // b*32 + co
    const int b = bco >> 5, co = bco & 31;
    const int tid = threadIdx.x;
    __shared__ float ws[64 * 9];
    for (int i = tid; i < 576; i += 256) {
        int ci = i / 9, kk = i % 9;
        ws[i] = w[(ci * 32 + co) * 9 + kk];
    }
    __syncthreads();
    const int pix = blockIdx.x * 256 + tid;      // 256*256 = 65536, gridDim.x=256
    const int ow = pix & 255, oh = pix >> 8;
    const bf16* ib = in + (long)b * 64 * 16384;
    float acc = bias[co];
    #pragma unroll
    for (int kh = 0; kh < 3; ++kh) {
        int t = oh + 1 - kh;
        if (t & 1) continue;
        int ih = t >> 1;
        if ((unsigned)ih >= 128u) continue;
        #pragma unroll
        for (int kw = 0; kw < 3; ++kw) {
            int u = ow + 1 - kw;
            if (u & 1) continue;
            int iw = u >> 1;
            if ((unsigned)iw >= 128u) continue;
            for (int ci = 0; ci < 64; ++ci)
                acc += ld(ib, (ci * 128 + ih) * 128 + iw) * ws[ci * 9 + kh * 3 + kw];
        }
    }
    out[((long)(b * 32 + co) * 256 + oh) * 256 + ow] = __float2bfloat16(fmaxf(acc, 0.f));
}

// ---------------- dec3 (convT s1 p1 == conv k3 p1) + MSE ----------------
__global__ __launch_bounds__(256) void dec3_mse_k(const bf16* __restrict__ in,
        const float* __restrict__ w, const float* __restrict__ bias,
        const float* __restrict__ x, float* __restrict__ acc) {
    __shared__ float ws[32 * 3 * 9];   // w[ci][co][kh][kw]
    __shared__ float lb[3];
    __shared__ float red[4];
    const int tid = threadIdx.x;
    for (int i = tid; i < 864; i += 256) ws[i] = w[i];
    if (tid < 3) lb[tid] = bias[tid];
    __syncthreads();
    const int pix = blockIdx.x * 256 + tid;      // C*65536 pixels total
    const int ow = pix & 255, oh = (pix >> 8) & 255, b = pix >> 16;
    const bf16* ib = in + (long)b * 32 * 65536;
    float r0 = lb[0], r1 = lb[1], r2 = lb[2];
    #pragma unroll
    for (int kh = 0; kh < 3; ++kh) {
        int ih = oh + 1 - kh;
        if ((unsigned)ih >= 256u) continue;
        #pragma unroll
        for (int kw = 0; kw < 3; ++kw) {
            int iw = ow + 1 - kw;
            if ((unsigned)iw >= 256u) continue;
            for (int ci = 0; ci < 32; ++ci) {
                float v = ld(ib, (ci * 256 + ih) * 256 + iw);
                r0 += v * ws[(ci * 3 + 0) * 9 + kh * 3 + kw];
                r1 += v * ws[(ci * 3 + 1) * 9 + kh * 3 + kw];
                r2 += v * ws[(ci * 3 + 2) * 9 + kh * 3 + kw];
            }
        }
    }
    const float* xb = x + (long)b * 3 * 65536;
    float d0 = r0 - xb[0 * 65536 + oh * 256 + ow];
    float d1 = r1 - xb[1 * 65536 + oh * 256 + ow];
    float d2 = r2 - xb[2 * 65536 + oh * 256 + ow];
    float lsum = d0 * d0 + d1 * d1 + d2 * d2;
    for (int off = 32; off > 0; off >>= 1) lsum += __shfl_down(lsum, off, 64);
    if ((tid & 63) == 0) red[tid >> 6] = lsum;
    __syncthreads();
    if (tid == 0) atomicAdd(&acc[1], red[0] + red[1] + red[2] + red[3]);
}

// ---------------- finalize ----------------
__global__ void finalize_k(const float* __restrict__ acc, float* __restrict__ out) {
    if (threadIdx.x == 0) {
        float eq  = 1.25f * acc[0] / 4194304.f;     // 262144 * 16 (full batch)
        float mse = acc[1] / 12582912.f;            // 64 * 3 * 256 * 256
        out[0] = eq;
        out[1] = mse;
        out[2] = mse;
    }
}

extern "C" void kernel_launch(void* const* d_in, const int* in_sizes, int n_in,
                              void* d_out, int out_size, void* d_ws, size_t ws_size,
                              hipStream_t stream) {
    (void)in_sizes; (void)n_in; (void)out_size;
    const float* x   = (const float*)d_in[0];
    const float* ew1 = (const float*)d_in[1];
    const float* eb1 = (const float*)d_in[2];
    const float* ew2 = (const float*)d_in[3];
    const float* eb2 = (const float*)d_in[4];
    const float* ew3 = (const float*)d_in[5];
    const float* eb3 = (const float*)d_in[6];
    const float* cb  = (const float*)d_in[7];
    const float* dw1 = (const float*)d_in[8];
    const float* db1 = (const float*)d_in[9];
    const float* dw2 = (const float*)d_in[10];
    const float* db2 = (const float*)d_in[11];
    const float* dw3 = (const float*)d_in[12];
    const float* db3 = (const float*)d_in[13];
    float* out = (float*)d_out;

    // Pick largest power-of-two chunk C (images per pass) that fits ws_size.
    // need(C) = 256 (acc) + C*262144 (ec fp32) + C*6291456 (reuse region:
    //           max(a1c+a2c, d1c+d2c) bf16) = 256 + C*6553600 bytes.
    int C = 64;
    while (C > 1 && (size_t)256 + (size_t)C * 6553600UL > ws_size) C >>= 1;

    char* base = (char*)d_ws;
    float* acc = (float*)base;
    float* ec  = (float*)(base + 256);
    char*  rgn = base + 256 + (size_t)C * 262144UL;
    bf16*  a1c = (bf16*)rgn;
    bf16*  a2c = (bf16*)(rgn + (size_t)C * 1048576UL);
    bf16*  d1c = (bf16*)rgn;                              // reuse (a1c,a2c dead)
    bf16*  d2c = (bf16*)(rgn + (size_t)C * 2097152UL);

    zero_k<<<1, 64, 0, stream>>>(acc);

    for (int b0 = 0; b0 < 64; b0 += C) {
        const float* xc = x + (size_t)b0 * 196608UL;   // 3*256*256 per image
        conv1_k   <<<dim3(64,  C * 32), 256, 0, stream>>>(xc,  ew1, eb1, a1c);
        conv2_k   <<<dim3(16,  C * 64), 256, 0, stream>>>(a1c, ew2, eb2, a2c);
        conv3_vq_k<<<dim3(C * 16),      256, 0, stream>>>(a2c, ew3, eb3, cb, ec, acc);
        dec1_k    <<<dim3(64,  C * 64), 256, 0, stream>>>(ec,  dw1, db1, d1c);
        dec2_k    <<<dim3(256, C * 32), 256, 0, stream>>>(d1c, dw2, db2, d2c);
        dec3_mse_k<<<dim3(C * 256),     256, 0, stream>>>(d2c, dw3, db3, xc, acc);
    }
    finalize_k<<<1, 64, 0, stream>>>(acc, out);
}

// Round 4
// 1559.048 us; speedup vs baseline: 7.8813x; 7.8813x over previous
//
#include <hip/hip_runtime.h>
#include <hip/hip_bf16.h>

// VQ-VAE forward — NHWC bf16 intermediates, MFMA (16x16x32 bf16) for all convs.
// Outputs: [1.25*vq_mse, recon_mse, recon_mse]
//
// MFMA lane layouts (gfx950, HW-verified per guide):
//   A: m = lane&15, k = (lane>>4)*8 + j     (8 bf16 / lane)
//   B: n = lane&15, k = (lane>>4)*8 + j
//   D: n = lane&15, m = (lane>>4)*4 + reg   (4 f32 / lane)
//
// Transposed convs use sub-pixel parity decomposition:
//   out(2i+ph, 2j+pw) = sum over (dh,dw) in class(ph,pw) of
//       in(i+dh, j+dw) * W[kh(ph,dh)][kw(pw,dw)]
//   C00: A00*W11 | C01: A01*W10 + A00*W12 | C10: A10*W01 + A00*W21
//   C11: A11*W00 + A10*W02 + A01*W20 + A00*W22

typedef __attribute__((ext_vector_type(8))) short bf16x8;
typedef __attribute__((ext_vector_type(4))) float f32x4;
typedef unsigned short ushort_t;

__device__ __forceinline__ ushort_t f2bf(float v) {
    __hip_bfloat16 h = __float2bfloat16(v);
    return *(ushort_t*)&h;
}
__device__ __forceinline__ float bf2f(ushort_t u) {
    __hip_bfloat16 h = *(__hip_bfloat16*)&u;
    return __bfloat162float(h);
}

// Transformed-weight layout in wbuf (elements of bf16):
//   W1T  @ 0      [co32][k32]            (k=ci*9+kh*3+kw, pad 27->32)
//   W2T  @ 1024   [t9][co64][ci32]
//   WD1  @ 19456  [t9][co64][k32]        (k<16 = ci, else 0)
//   WD2  @ 37888  [t9][kc2][co32][ci32]
//   WD3  @ 56320  [t9][co16][ci32]       (taps FLIPPED: src 8-t; co>=3 -> 0)
//   cn (fp32, 512) @ byte offset 121856

__global__ void zero_k(float* __restrict__ acc) { acc[threadIdx.x] = 0.f; }

__global__ __launch_bounds__(256) void prep_k(
        const float* __restrict__ ew1, const float* __restrict__ ew2,
        const float* __restrict__ dw1, const float* __restrict__ dw2,
        const float* __restrict__ dw3, const float* __restrict__ cb,
        ushort_t* __restrict__ wt, float* __restrict__ cn) {
    int idx = blockIdx.x * 256 + threadIdx.x;
    if (idx < 1024) {
        int co = idx >> 5, k = idx & 31;
        wt[idx] = (k < 27) ? f2bf(ew1[co * 27 + k]) : (ushort_t)0;
    } else if (idx < 19456) {
        int i = idx - 1024;
        int t = i >> 11, co = (i >> 5) & 63, ci = i & 31;
        wt[idx] = f2bf(ew2[co * 288 + ci * 9 + t]);
    } else if (idx < 37888) {
        int i = idx - 19456;
        int t = i >> 11, co = (i >> 5) & 63, k = i & 31;
        wt[idx] = (k < 16) ? f2bf(dw1[k * 576 + co * 9 + t]) : (ushort_t)0;
    } else if (idx < 56320) {
        int i = idx - 37888;
        int t = i >> 11, kc = (i >> 10) & 1, co = (i >> 5) & 31, ci = i & 31;
        wt[idx] = f2bf(dw2[(kc * 32 + ci) * 288 + co * 9 + t]);
    } else if (idx < 60928) {
        int i = idx - 56320;
        int t = i >> 9, co = (i >> 5) & 15, ci = i & 31;
        wt[idx] = (co < 3) ? f2bf(dw3[ci * 27 + co * 9 + (8 - t)]) : (ushort_t)0;
    } else if (idx < 61440) {
        int k = idx - 60928;
        float s = 0.f;
        #pragma unroll
        for (int d = 0; d < 16; ++d) { float v = cb[k * 16 + d]; s += v * v; }
        cn[k] = s;
    }
}

// ---------------- conv1 MFMA: x NCHW fp32 -> a1 NHWC bf16 [B,128,128,32] ----
__global__ __launch_bounds__(256, 1) void conv1_k(const float* __restrict__ x,
        const ushort_t* __restrict__ wt, const float* __restrict__ bias,
        ushort_t* __restrict__ a1) {
    const int by = blockIdx.y, b = by >> 7, oh = by & 127;
    const int tid = threadIdx.x;
    __shared__ __align__(16) ushort_t sA[128 * 40];   // [m128][k32 pad40]
    #pragma unroll
    for (int it = 0; it < 16; ++it) {
        int slot = it * 256 + tid;                    // 4096 = 128m * 32k
        int m = slot >> 5, k = slot & 31;
        float v = 0.f;
        if (k < 27) {
            int ci = k / 9, r9 = k % 9, kh = r9 / 3, kw = r9 % 3;
            int ih = 2 * oh + kh - 1, iw = 2 * m + kw - 1;
            if ((unsigned)ih < 256u && (unsigned)iw < 256u)
                v = x[(long)(b * 3 + ci) * 65536 + ih * 256 + iw];
        }
        sA[m * 40 + k] = f2bf(v);
    }
    __syncthreads();
    const int lane = tid & 63, wave = tid >> 6, q = lane >> 4, n16 = lane & 15;
    bf16x8 Bw[2];
    #pragma unroll
    for (int u = 0; u < 2; ++u)
        Bw[u] = *(const bf16x8*)(wt + (u * 16 + n16) * 32 + q * 8);
    f32x4 acc[2][2];
    #pragma unroll
    for (int u = 0; u < 2; ++u) {
        float bz = bias[u * 16 + n16];
        acc[0][u] = (f32x4){bz, bz, bz, bz};
        acc[1][u] = (f32x4){bz, bz, bz, bz};
    }
    #pragma unroll
    for (int mf = 0; mf < 2; ++mf) {
        bf16x8 A = *(bf16x8*)&sA[(wave * 32 + mf * 16 + n16) * 40 + q * 8];
        #pragma unroll
        for (int u = 0; u < 2; ++u)
            acc[mf][u] = __builtin_amdgcn_mfma_f32_16x16x32_bf16(A, Bw[u], acc[mf][u], 0, 0, 0);
    }
    #pragma unroll
    for (int mf = 0; mf < 2; ++mf)
        #pragma unroll
        for (int u = 0; u < 2; ++u)
            #pragma unroll
            for (int r = 0; r < 4; ++r) {
                int ow = wave * 32 + mf * 16 + q * 4 + r;
                a1[((long)(b * 128 + oh) * 128 + ow) * 32 + u * 16 + n16] =
                    f2bf(fmaxf(acc[mf][u][r], 0.f));
            }
}

// ---------------- conv2 MFMA: a1 -> a2 NHWC [B,64,64,64] --------------------
__global__ __launch_bounds__(256, 1) void conv2_k(const ushort_t* __restrict__ a1,
        const ushort_t* __restrict__ wt, const float* __restrict__ bias,
        ushort_t* __restrict__ a2) {
    const int by = blockIdx.y, b = by >> 6, oh = by & 63;
    const int tid = threadIdx.x;
    // parity-split: [kh3][p2][c66][ci32 pad40]
    __shared__ __align__(16) ushort_t sA[3 * 2 * 66 * 40];
    uint4* z4 = (uint4*)sA;
    #pragma unroll
    for (int it = 0; it < 8; ++it) {
        int slot = it * 256 + tid;
        if (slot < 1980) z4[slot] = (uint4){0, 0, 0, 0};
    }
    __syncthreads();
    #pragma unroll
    for (int it = 0; it < 6; ++it) {
        int slot = it * 256 + tid;                    // 1536 = 3kh*128iw*4
        if (slot < 1536) {
            int kh = slot >> 9, rem = slot & 511, iw = rem >> 2, ci8 = (rem & 3) << 3;
            int ih = 2 * oh + kh - 1;
            if ((unsigned)ih < 128u) {
                uint4 v = *(const uint4*)(a1 + ((long)(b * 128 + ih) * 128 + iw) * 32 + ci8);
                int idx = iw + 2, p = idx & 1, c = idx >> 1;
                *(uint4*)&sA[((kh * 2 + p) * 66 + c) * 40 + ci8] = v;
            }
        }
    }
    __syncthreads();
    const int lane = tid & 63, wave = tid >> 6, q = lane >> 4, n16 = lane & 15;
    bf16x8 Bw[9][4];
    #pragma unroll
    for (int t = 0; t < 9; ++t)
        #pragma unroll
        for (int u = 0; u < 4; ++u)
            Bw[t][u] = *(const bf16x8*)(wt + 1024 + t * 2048 + (u * 16 + n16) * 32 + q * 8);
    f32x4 acc[4];
    #pragma unroll
    for (int u = 0; u < 4; ++u) {
        float bz = bias[u * 16 + n16];
        acc[u] = (f32x4){bz, bz, bz, bz};
    }
    const int ow = wave * 16 + n16;   // A row (m)
    #pragma unroll
    for (int t = 0; t < 9; ++t) {
        const int kh = t / 3, kw = t % 3;
        const int p = (kw == 1) ? 0 : 1;
        const int c = (kw == 0) ? ow : ow + 1;
        bf16x8 A = *(bf16x8*)&sA[((kh * 2 + p) * 66 + c) * 40 + q * 8];
        #pragma unroll
        for (int u = 0; u < 4; ++u)
            acc[u] = __builtin_amdgcn_mfma_f32_16x16x32_bf16(A, Bw[t][u], acc[u], 0, 0, 0);
    }
    #pragma unroll
    for (int u = 0; u < 4; ++u)
        #pragma unroll
        for (int r = 0; r < 4; ++r) {
            int owo = wave * 16 + q * 4 + r;
            a2[((long)(b * 64 + oh) * 64 + owo) * 64 + u * 16 + n16] =
                f2bf(fmaxf(acc[u][r], 0.f));
        }
}

// ---------------- conv3 (1x1) + VQ + loss: a2 -> e NHWC bf16 [B,64,64,16] ---
__global__ __launch_bounds__(256) void conv3_vq_k(const ushort_t* __restrict__ a2,
        const float* __restrict__ w3, const float* __restrict__ b3,
        const float* __restrict__ cb, const float* __restrict__ cn,
        ushort_t* __restrict__ e, float* __restrict__ acc) {
    const int px = blockIdx.x * 256 + threadIdx.x;
    const ushort_t* arow = a2 + (long)px * 64;
    float z[16];
    #pragma unroll
    for (int d = 0; d < 16; ++d) z[d] = b3[d];
    for (int c8 = 0; c8 < 8; ++c8) {
        uint4 raw = *(const uint4*)(arow + c8 * 8);
        ushort_t us[8];
        *(uint4*)us = raw;
        #pragma unroll
        for (int j = 0; j < 8; ++j) {
            float a = bf2f(us[j]);
            #pragma unroll
            for (int d = 0; d < 16; ++d)
                z[d] = fmaf(a, w3[d * 64 + c8 * 8 + j], z[d]);
        }
    }
    const float4* cb4 = (const float4*)cb;
    float best = 1e30f; int bi = 0;
    for (int k = 0; k < 512; ++k) {
        float4 c0 = cb4[k * 4 + 0], c1 = cb4[k * 4 + 1];
        float4 c2 = cb4[k * 4 + 2], c3 = cb4[k * 4 + 3];
        float d0 = z[0]*c0.x + z[1]*c0.y + z[2]*c0.z + z[3]*c0.w;
        float d1 = z[4]*c1.x + z[5]*c1.y + z[6]*c1.z + z[7]*c1.w;
        float d2 = z[8]*c2.x + z[9]*c2.y + z[10]*c2.z + z[11]*c2.w;
        float d3 = z[12]*c3.x + z[13]*c3.y + z[14]*c3.z + z[15]*c3.w;
        float dist = cn[k] - 2.f * (d0 + d1 + d2 + d3);
        if (dist < best) { best = dist; bi = k; }
    }
    float lsum = 0.f;
    #pragma unroll
    for (int d = 0; d < 16; ++d) {
        float qv = cb[bi * 16 + d];
        float df = qv - z[d];
        lsum += df * df;
        e[(long)px * 16 + d] = f2bf(qv);
    }
    #pragma unroll
    for (int off = 32; off > 0; off >>= 1) lsum += __shfl_down(lsum, off, 64);
    if ((threadIdx.x & 63) == 0) atomicAdd(&acc[0], lsum);
}

// ---------------- dec1 MFMA: e -> d1 NHWC [B,128,128,64] --------------------
__global__ __launch_bounds__(256, 1) void dec1_k(const ushort_t* __restrict__ e,
        const ushort_t* __restrict__ wt, const float* __restrict__ bias,
        ushort_t* __restrict__ d1) {
    const int by = blockIdx.y, b = by >> 6, i = by & 63;
    const int tid = threadIdx.x;
    __shared__ __align__(16) ushort_t sE[2 * 66 * 24];  // [dh2][j66][ci16 pad24]
    uint4* z4 = (uint4*)sE;
    #pragma unroll
    for (int it = 0; it < 2; ++it) {
        int slot = it * 256 + tid;
        if (slot < 396) z4[slot] = (uint4){0, 0, 0, 0};
    }
    __syncthreads();
    {
        int dh = tid >> 7, rem = tid & 127, j = rem >> 1, ci8 = (rem & 1) * 8;
        if (i + dh < 64) {
            uint4 v = *(const uint4*)(e + ((long)((b * 64 + i + dh) * 64 + j)) * 16 + ci8);
            *(uint4*)&sE[(dh * 66 + j) * 24 + ci8] = v;
        }
    }
    __syncthreads();
    const int lane = tid & 63, wave = tid >> 6, q = lane >> 4, n16 = lane & 15;
    bf16x8 Bw[9][4];
    #pragma unroll
    for (int t = 0; t < 9; ++t)
        #pragma unroll
        for (int u = 0; u < 4; ++u)
            Bw[t][u] = *(const bf16x8*)(wt + 19456 + t * 2048 + (u * 16 + n16) * 32 + q * 8);
    f32x4 acc[4][4];   // [class ph*2+pw][ntile]
    #pragma unroll
    for (int u = 0; u < 4; ++u) {
        float bz = bias[u * 16 + n16];
        #pragma unroll
        for (int c = 0; c < 4; ++c) acc[c][u] = (f32x4){bz, bz, bz, bz};
    }
    const int jl = wave * 16 + n16;
    bf16x8 A[2][2];
    #pragma unroll
    for (int dh = 0; dh < 2; ++dh)
        #pragma unroll
        for (int dw = 0; dw < 2; ++dw)
            A[dh][dw] = *(bf16x8*)&sE[(dh * 66 + jl + dw) * 24 + (q & 1) * 8];
#define MF1(cls, dh, dw, kh, kw)                                                     \
    _Pragma("unroll")                                                                \
    for (int u = 0; u < 4; ++u)                                                      \
        acc[cls][u] = __builtin_amdgcn_mfma_f32_16x16x32_bf16(                       \
            A[dh][dw], Bw[(kh) * 3 + (kw)][u], acc[cls][u], 0, 0, 0);
    MF1(0, 0, 0, 1, 1)
    MF1(1, 0, 1, 1, 0)  MF1(1, 0, 0, 1, 2)
    MF1(2, 1, 0, 0, 1)  MF1(2, 0, 0, 2, 1)
    MF1(3, 1, 1, 0, 0)  MF1(3, 1, 0, 0, 2)  MF1(3, 0, 1, 2, 0)  MF1(3, 0, 0, 2, 2)
#undef MF1
    #pragma unroll
    for (int ph = 0; ph < 2; ++ph)
        #pragma unroll
        for (int pw = 0; pw < 2; ++pw)
            #pragma unroll
            for (int u = 0; u < 4; ++u)
                #pragma unroll
                for (int r = 0; r < 4; ++r) {
                    int oh = 2 * i + ph;
                    int ow = 2 * (wave * 16 + q * 4 + r) + pw;
                    d1[((long)(b * 128 + oh) * 128 + ow) * 64 + u * 16 + n16] =
                        f2bf(fmaxf(acc[ph * 2 + pw][u][r], 0.f));
                }
}

// ---------------- dec2 MFMA: d1 -> d2 NHWC [B,256,256,32] -------------------
__global__ __launch_bounds__(256, 1) void dec2_k(const ushort_t* __restrict__ d1,
        const ushort_t* __restrict__ wt, const float* __restrict__ bias,
        ushort_t* __restrict__ d2) {
    const int by = blockIdx.y, b = by >> 7, i = by & 127;
    const int j0 = blockIdx.x * 64;
    const int tid = threadIdx.x;
    __shared__ __align__(16) ushort_t sD[2 * 66 * 72];  // [dh2][j66][ci64 pad72]
    uint4* z4 = (uint4*)sD;
    #pragma unroll
    for (int it = 0; it < 5; ++it) {
        int slot = it * 256 + tid;
        if (slot < 1188) z4[slot] = (uint4){0, 0, 0, 0};
    }
    __syncthreads();
    #pragma unroll
    for (int it = 0; it < 5; ++it) {
        int slot = it * 256 + tid;                    // 1040 = 2dh*65jj*8
        if (slot < 1040) {
            int dh = slot / 520, rem = slot % 520, jj = rem / 8, ci8 = (rem % 8) * 8;
            int j = j0 + jj;
            if (i + dh < 128 && j < 128) {
                uint4 v = *(const uint4*)(d1 + ((long)((b * 128 + i + dh) * 128 + j)) * 64 + ci8);
                *(uint4*)&sD[(dh * 66 + jj) * 72 + ci8] = v;
            }
        }
    }
    __syncthreads();
    const int lane = tid & 63, wave = tid >> 6, q = lane >> 4, n16 = lane & 15;
    bf16x8 Bw[9][2][2];   // [tap][kc][ntile]
    #pragma unroll
    for (int t = 0; t < 9; ++t)
        #pragma unroll
        for (int kc = 0; kc < 2; ++kc)
            #pragma unroll
            for (int u = 0; u < 2; ++u)
                Bw[t][kc][u] = *(const bf16x8*)(wt + 37888 + t * 2048 + kc * 1024 +
                                                (u * 16 + n16) * 32 + q * 8);
    f32x4 acc[4][2];
    #pragma unroll
    for (int u = 0; u < 2; ++u) {
        float bz = bias[u * 16 + n16];
        #pragma unroll
        for (int c = 0; c < 4; ++c) acc[c][u] = (f32x4){bz, bz, bz, bz};
    }
    const int jl = wave * 16 + n16;
    #pragma unroll
    for (int kc = 0; kc < 2; ++kc) {
        bf16x8 A[2][2];
        #pragma unroll
        for (int dh = 0; dh < 2; ++dh)
            #pragma unroll
            for (int dw = 0; dw < 2; ++dw)
                A[dh][dw] = *(bf16x8*)&sD[(dh * 66 + jl + dw) * 72 + kc * 32 + q * 8];
#define MF2(cls, dh, dw, kh, kw)                                                     \
        _Pragma("unroll")                                                            \
        for (int u = 0; u < 2; ++u)                                                  \
            acc[cls][u] = __builtin_amdgcn_mfma_f32_16x16x32_bf16(                   \
                A[dh][dw], Bw[(kh) * 3 + (kw)][kc][u], acc[cls][u], 0, 0, 0);
        MF2(0, 0, 0, 1, 1)
        MF2(1, 0, 1, 1, 0)  MF2(1, 0, 0, 1, 2)
        MF2(2, 1, 0, 0, 1)  MF2(2, 0, 0, 2, 1)
        MF2(3, 1, 1, 0, 0)  MF2(3, 1, 0, 0, 2)  MF2(3, 0, 1, 2, 0)  MF2(3, 0, 0, 2, 2)
#undef MF2
    }
    #pragma unroll
    for (int ph = 0; ph < 2; ++ph)
        #pragma unroll
        for (int pw = 0; pw < 2; ++pw)
            #pragma unroll
            for (int u = 0; u < 2; ++u)
                #pragma unroll
                for (int r = 0; r < 4; ++r) {
                    int oh = 2 * i + ph;
                    int ow = 2 * (j0 + wave * 16 + q * 4 + r) + pw;
                    d2[((long)(b * 256 + oh) * 256 + ow) * 32 + u * 16 + n16] =
                        f2bf(fmaxf(acc[ph * 2 + pw][u][r], 0.f));
                }
}

// ---------------- dec3 MFMA (conv k3 p1, flipped W) + fused MSE -------------
__global__ __launch_bounds__(256, 1) void dec3_mse_k(const ushort_t* __restrict__ d2,
        const ushort_t* __restrict__ wt, const float* __restrict__ bias,
        const float* __restrict__ x, float* __restrict__ acc) {
    const int by = blockIdx.y, b = by >> 8, oh = by & 255;
    const int tid = threadIdx.x;
    __shared__ __align__(16) ushort_t sC[3 * 258 * 40];  // [kh3][c258][ci32 pad40]
    uint4* z4 = (uint4*)sC;
    #pragma unroll
    for (int it = 0; it < 16; ++it) {
        int slot = it * 256 + tid;
        if (slot < 3870) z4[slot] = (uint4){0, 0, 0, 0};
    }
    __syncthreads();
    #pragma unroll
    for (int it = 0; it < 12; ++it) {
        int slot = it * 256 + tid;                    // 3072 = 3kh*256iw*4
        int kh = slot >> 10, rem = slot & 1023, iw = rem >> 2, ci8 = (rem & 3) << 3;
        int ih = oh + kh - 1;
        if ((unsigned)ih < 256u) {
            uint4 v = *(const uint4*)(d2 + ((long)((b * 256 + ih) * 256 + iw)) * 32 + ci8);
            *(uint4*)&sC[(kh * 258 + iw + 1) * 40 + ci8] = v;
        }
    }
    __syncthreads();
    const int lane = tid & 63, wave = tid >> 6, q = lane >> 4, n16 = lane & 15;
    bf16x8 Bw[9];
    #pragma unroll
    for (int t = 0; t < 9; ++t)
        Bw[t] = *(const bf16x8*)(wt + 56320 + t * 512 + n16 * 32 + q * 8);
    float bz = (n16 < 3) ? bias[n16] : 0.f;
    f32x4 acc4[4];
    #pragma unroll
    for (int mf = 0; mf < 4; ++mf) acc4[mf] = (f32x4){bz, bz, bz, bz};
    #pragma unroll
    for (int t = 0; t < 9; ++t) {
        const int kh = t / 3, kw = t % 3;
        #pragma unroll
        for (int mf = 0; mf < 4; ++mf) {
            int ow = wave * 64 + mf * 16 + n16;
            bf16x8 A = *(bf16x8*)&sC[(kh * 258 + ow + kw) * 40 + q * 8];
            acc4[mf] = __builtin_amdgcn_mfma_f32_16x16x32_bf16(A, Bw[t], acc4[mf], 0, 0, 0);
        }
    }
    float lsum = 0.f;
    if (n16 < 3) {
        #pragma unroll
        for (int mf = 0; mf < 4; ++mf)
            #pragma unroll
            for (int r = 0; r < 4; ++r) {
                int ow = wave * 64 + mf * 16 + q * 4 + r;
                float df = acc4[mf][r] - x[((long)(b * 3 + n16) * 256 + oh) * 256 + ow];
                lsum += df * df;
            }
    }
    #pragma unroll
    for (int off = 32; off > 0; off >>= 1) lsum += __shfl_down(lsum, off, 64);
    if (lane == 0) atomicAdd(&acc[1], lsum);
}

__global__ void finalize_k(const float* __restrict__ acc, float* __restrict__ out) {
    if (threadIdx.x == 0) {
        float eq  = 1.25f * acc[0] / 4194304.f;     // 262144 px * 16 d
        float mse = acc[1] / 12582912.f;            // 64 * 3 * 256 * 256
        out[0] = eq;
        out[1] = mse;
        out[2] = mse;
    }
}

extern "C" void kernel_launch(void* const* d_in, const int* in_sizes, int n_in,
                              void* d_out, int out_size, void* d_ws, size_t ws_size,
                              hipStream_t stream) {
    (void)in_sizes; (void)n_in; (void)out_size;
    const float* x   = (const float*)d_in[0];
    const float* ew1 = (const float*)d_in[1];
    const float* eb1 = (const float*)d_in[2];
    const float* ew2 = (const float*)d_in[3];
    const float* eb2 = (const float*)d_in[4];
    const float* ew3 = (const float*)d_in[5];
    const float* eb3 = (const float*)d_in[6];
    const float* cb  = (const float*)d_in[7];
    const float* dw1 = (const float*)d_in[8];
    const float* db1 = (const float*)d_in[9];
    const float* dw2 = (const float*)d_in[10];
    const float* db2 = (const float*)d_in[11];
    const float* dw3 = (const float*)d_in[12];
    const float* db3 = (const float*)d_in[13];
    float* out = (float*)d_out;

    // need(C) = 256(acc) + 131072(wbuf) + C*(131072 e + 6291456 region)
    int C = 64;
    while (C > 1 && (size_t)131328 + (size_t)C * 6422528UL > ws_size) C >>= 1;

    char* base = (char*)d_ws;
    float*    acc = (float*)base;
    ushort_t* wt  = (ushort_t*)(base + 256);
    float*    cn  = (float*)(base + 256 + 121856);
    ushort_t* e   = (ushort_t*)(base + 131328);
    char*     rgn = base + 131328 + (size_t)C * 131072UL;
    ushort_t* a1  = (ushort_t*)rgn;
    ushort_t* a2  = (ushort_t*)(rgn + (size_t)C * 1048576UL);
    ushort_t* dd1 = (ushort_t*)rgn;                          // reuse
    ushort_t* dd2 = (ushort_t*)(rgn + (size_t)C * 2097152UL);

    zero_k<<<1, 64, 0, stream>>>(acc);
    prep_k<<<240, 256, 0, stream>>>(ew1, ew2, dw1, dw2, dw3, cb, wt, cn);

    for (int b0 = 0; b0 < 64; b0 += C) {
        const float* xc = x + (size_t)b0 * 196608UL;
        conv1_k   <<<dim3(1, C * 128), 256, 0, stream>>>(xc,  wt, eb1, a1);
        conv2_k   <<<dim3(1, C * 64),  256, 0, stream>>>(a1,  wt, eb2, a2);
        conv3_vq_k<<<dim3(C * 16),     256, 0, stream>>>(a2,  ew3, eb3, cb, cn, e, acc);
        dec1_k    <<<dim3(1, C * 64),  256, 0, stream>>>(e,   wt, db1, dd1);
        dec2_k    <<<dim3(2, C * 128), 256, 0, stream>>>(dd1, wt, db2, dd2);
        dec3_mse_k<<<dim3(1, C * 256), 256, 0, stream>>>(dd2, wt, db3, xc, acc);
    }
    finalize_k<<<1, 64, 0, stream>>>(acc, out);
}

// Round 5
// 1134.787 us; speedup vs baseline: 10.8279x; 1.3739x over previous
//
#include <hip/hip_runtime.h>
#include <hip/hip_bf16.h>

// VQ-VAE forward — NHWC bf16 intermediates, MFMA (16x16x32 bf16) for all convs.
// Outputs: [1.25*vq_mse, recon_mse, recon_mse]
//
// MFMA lane layouts (gfx950, HW-verified per guide):
//   A: m = lane&15, k = (lane>>4)*8 + j     (8 bf16 / lane)
//   B: n = lane&15, k = (lane>>4)*8 + j
//   D: n = lane&15, m = (lane>>4)*4 + reg   (4 f32 / lane)
//
// Transposed convs use sub-pixel parity decomposition; each tap (kh,kw)
// belongs to exactly one output parity class:
//   cls = ((kh!=1)<<1)|(kw!=1), dh = (kh==0), dw = (kw==0)

typedef __attribute__((ext_vector_type(8))) short bf16x8;
typedef __attribute__((ext_vector_type(4))) float f32x4;
typedef unsigned short ushort_t;

__device__ __forceinline__ ushort_t f2bf(float v) {
    __hip_bfloat16 h = __float2bfloat16(v);
    return *(ushort_t*)&h;
}
__device__ __forceinline__ float bf2f(ushort_t u) {
    __hip_bfloat16 h = *(__hip_bfloat16*)&u;
    return __bfloat162float(h);
}

// Transformed-weight layout in wbuf (elements of bf16):
//   W1T  @ 0      [co32][k32]            (k=ci*9+kh*3+kw, pad 27->32)
//   W2T  @ 1024   [t9][co64][ci32]
//   WD1  @ 19456  [t9][co64][k32]        (k<16 = ci, else 0)
//   WD2  @ 37888  [t9][kc2][co32][ci32]
//   WD3  @ 56320  [t9][co16][ci32]       (taps FLIPPED: src 8-t; co>=3 -> 0)
//   cn (fp32, 512) @ byte offset 121856

__global__ void zero_k(float* __restrict__ acc) { acc[threadIdx.x] = 0.f; }

__global__ __launch_bounds__(256) void prep_k(
        const float* __restrict__ ew1, const float* __restrict__ ew2,
        const float* __restrict__ dw1, const float* __restrict__ dw2,
        const float* __restrict__ dw3, const float* __restrict__ cb,
        ushort_t* __restrict__ wt, float* __restrict__ cn) {
    int idx = blockIdx.x * 256 + threadIdx.x;
    if (idx < 1024) {
        int co = idx >> 5, k = idx & 31;
        wt[idx] = (k < 27) ? f2bf(ew1[co * 27 + k]) : (ushort_t)0;
    } else if (idx < 19456) {
        int i = idx - 1024;
        int t = i >> 11, co = (i >> 5) & 63, ci = i & 31;
        wt[idx] = f2bf(ew2[co * 288 + ci * 9 + t]);
    } else if (idx < 37888) {
        int i = idx - 19456;
        int t = i >> 11, co = (i >> 5) & 63, k = i & 31;
        wt[idx] = (k < 16) ? f2bf(dw1[k * 576 + co * 9 + t]) : (ushort_t)0;
    } else if (idx < 56320) {
        int i = idx - 37888;
        int t = i >> 11, kc = (i >> 10) & 1, co = (i >> 5) & 31, ci = i & 31;
        wt[idx] = f2bf(dw2[(kc * 32 + ci) * 288 + co * 9 + t]);
    } else if (idx < 60928) {
        int i = idx - 56320;
        int t = i >> 9, co = (i >> 5) & 15, ci = i & 31;
        wt[idx] = (co < 3) ? f2bf(dw3[ci * 27 + co * 9 + (8 - t)]) : (ushort_t)0;
    } else if (idx < 61440) {
        int k = idx - 60928;
        float s = 0.f;
        #pragma unroll
        for (int d = 0; d < 16; ++d) { float v = cb[k * 16 + d]; s += v * v; }
        cn[k] = s;
    }
}

// ---------------- conv1 MFMA: x NCHW fp32 -> a1 NHWC bf16 [B,128,128,32] ----
__global__ __launch_bounds__(256, 4) void conv1_k(const float* __restrict__ x,
        const ushort_t* __restrict__ wt, const float* __restrict__ bias,
        ushort_t* __restrict__ a1) {
    const int by = blockIdx.y, b = by >> 7, oh = by & 127;
    const int tid = threadIdx.x;
    __shared__ __align__(16) ushort_t sX[9 * 264];   // [ci*3+kh][iw+1 (258 used)]
    __shared__ int sOff[32];
    for (int i = tid; i < 9 * 264 / 2; i += 256) ((unsigned*)sX)[i] = 0u;
    if (tid < 32) {
        int k = tid, off = 0;
        if (k < 27) { int ci = k / 9, r9 = k % 9, kh = r9 / 3, kw = r9 % 3;
                      off = (ci * 3 + kh) * 264 + kw; }
        sOff[tid] = off;
    }
    __syncthreads();
    #pragma unroll
    for (int it = 0; it < 9; ++it) {
        int slot = it * 256 + tid;                  // 2304 = 3ci * 3kh * 256iw
        int ci = slot / 768, r = slot % 768, kh = r >> 8, iw = r & 255;
        int ih = 2 * oh + kh - 1;
        float v = ((unsigned)ih < 256u) ? x[(long)(b * 3 + ci) * 65536 + ih * 256 + iw] : 0.f;
        sX[(ci * 3 + kh) * 264 + iw + 1] = f2bf(v);
    }
    __syncthreads();
    const int lane = tid & 63, wave = tid >> 6, q = lane >> 4, n16 = lane & 15;
    bf16x8 Bw[2];
    #pragma unroll
    for (int u = 0; u < 2; ++u)
        Bw[u] = *(const bf16x8*)(wt + (u * 16 + n16) * 32 + q * 8);
    f32x4 acc[2][2];
    #pragma unroll
    for (int u = 0; u < 2; ++u) {
        float bz = bias[u * 16 + n16];
        acc[0][u] = (f32x4){bz, bz, bz, bz};
        acc[1][u] = (f32x4){bz, bz, bz, bz};
    }
    #pragma unroll
    for (int mf = 0; mf < 2; ++mf) {
        const int m2 = 2 * (wave * 32 + mf * 16 + n16);
        ushort_t av[8];
        #pragma unroll
        for (int j = 0; j < 8; ++j) {
            int k = q * 8 + j;
            av[j] = (k < 27) ? sX[sOff[k] + m2] : (ushort_t)0;
        }
        bf16x8 A = *(bf16x8*)av;
        #pragma unroll
        for (int u = 0; u < 2; ++u)
            acc[mf][u] = __builtin_amdgcn_mfma_f32_16x16x32_bf16(A, Bw[u], acc[mf][u], 0, 0, 0);
    }
    #pragma unroll
    for (int mf = 0; mf < 2; ++mf)
        #pragma unroll
        for (int u = 0; u < 2; ++u)
            #pragma unroll
            for (int r = 0; r < 4; ++r) {
                int ow = wave * 32 + mf * 16 + q * 4 + r;
                a1[((long)(b * 128 + oh) * 128 + ow) * 32 + u * 16 + n16] =
                    f2bf(fmaxf(acc[mf][u][r], 0.f));
            }
}

// ---------------- conv2 MFMA: a1 -> a2 NHWC [B,64,64,64] --------------------
__global__ __launch_bounds__(256, 4) void conv2_k(const ushort_t* __restrict__ a1,
        const ushort_t* __restrict__ wt, const float* __restrict__ bias,
        ushort_t* __restrict__ a2) {
    const int by = blockIdx.y, b = by >> 6, oh = by & 63;
    const int tid = threadIdx.x;
    // parity-split: [kh3][p2][c66][ci32 pad40]
    __shared__ __align__(16) ushort_t sA[3 * 2 * 66 * 40];
    uint4* z4 = (uint4*)sA;
    #pragma unroll
    for (int it = 0; it < 8; ++it) {
        int slot = it * 256 + tid;
        if (slot < 1980) z4[slot] = (uint4){0, 0, 0, 0};
    }
    __syncthreads();
    #pragma unroll
    for (int it = 0; it < 6; ++it) {
        int slot = it * 256 + tid;                    // 1536 = 3kh*128iw*4
        if (slot < 1536) {
            int kh = slot >> 9, rem = slot & 511, iw = rem >> 2, ci8 = (rem & 3) << 3;
            int ih = 2 * oh + kh - 1;
            if ((unsigned)ih < 128u) {
                uint4 v = *(const uint4*)(a1 + ((long)(b * 128 + ih) * 128 + iw) * 32 + ci8);
                int idx = iw + 2, p = idx & 1, c = idx >> 1;
                *(uint4*)&sA[((kh * 2 + p) * 66 + c) * 40 + ci8] = v;
            }
        }
    }
    __syncthreads();
    const int lane = tid & 63, wave = tid >> 6, q = lane >> 4, n16 = lane & 15;
    f32x4 acc[4];
    #pragma unroll
    for (int u = 0; u < 4; ++u) {
        float bz = bias[u * 16 + n16];
        acc[u] = (f32x4){bz, bz, bz, bz};
    }
    const int ow = wave * 16 + n16;   // A row (m)
    #pragma unroll
    for (int t = 0; t < 9; ++t) {
        const int kh = t / 3, kw = t % 3;
        const int p = (kw == 1) ? 0 : 1;
        const int c = (kw == 0) ? ow : ow + 1;
        bf16x8 A = *(bf16x8*)&sA[((kh * 2 + p) * 66 + c) * 40 + q * 8];
        #pragma unroll
        for (int u = 0; u < 4; ++u) {
            bf16x8 B = *(const bf16x8*)(wt + 1024 + t * 2048 + (u * 16 + n16) * 32 + q * 8);
            acc[u] = __builtin_amdgcn_mfma_f32_16x16x32_bf16(A, B, acc[u], 0, 0, 0);
        }
    }
    #pragma unroll
    for (int u = 0; u < 4; ++u)
        #pragma unroll
        for (int r = 0; r < 4; ++r) {
            int owo = wave * 16 + q * 4 + r;
            a2[((long)(b * 64 + oh) * 64 + owo) * 64 + u * 16 + n16] =
                f2bf(fmaxf(acc[u][r], 0.f));
        }
}

// ---------------- conv3 (1x1) + VQ + loss: a2 -> e NHWC bf16 [B,64,64,16] ---
__global__ __launch_bounds__(256) void conv3_vq_k(const ushort_t* __restrict__ a2,
        const float* __restrict__ w3, const float* __restrict__ b3,
        const float* __restrict__ cb, const float* __restrict__ cn,
        ushort_t* __restrict__ e, float* __restrict__ acc) {
    const int px = blockIdx.x * 256 + threadIdx.x;
    const ushort_t* arow = a2 + (long)px * 64;
    float z[16];
    #pragma unroll
    for (int d = 0; d < 16; ++d) z[d] = b3[d];
    for (int c8 = 0; c8 < 8; ++c8) {
        uint4 raw = *(const uint4*)(arow + c8 * 8);
        ushort_t us[8];
        *(uint4*)us = raw;
        #pragma unroll
        for (int j = 0; j < 8; ++j) {
            float a = bf2f(us[j]);
            #pragma unroll
            for (int d = 0; d < 16; ++d)
                z[d] = fmaf(a, w3[d * 64 + c8 * 8 + j], z[d]);
        }
    }
    const float4* cb4 = (const float4*)cb;
    float best = 1e30f; int bi = 0;
    for (int k = 0; k < 512; ++k) {
        float4 c0 = cb4[k * 4 + 0], c1 = cb4[k * 4 + 1];
        float4 c2 = cb4[k * 4 + 2], c3 = cb4[k * 4 + 3];
        float d0 = z[0]*c0.x + z[1]*c0.y + z[2]*c0.z + z[3]*c0.w;
        float d1 = z[4]*c1.x + z[5]*c1.y + z[6]*c1.z + z[7]*c1.w;
        float d2 = z[8]*c2.x + z[9]*c2.y + z[10]*c2.z + z[11]*c2.w;
        float d3 = z[12]*c3.x + z[13]*c3.y + z[14]*c3.z + z[15]*c3.w;
        float dist = cn[k] - 2.f * (d0 + d1 + d2 + d3);
        if (dist < best) { best = dist; bi = k; }
    }
    float lsum = 0.f;
    #pragma unroll
    for (int d = 0; d < 16; ++d) {
        float qv = cb[bi * 16 + d];
        float df = qv - z[d];
        lsum += df * df;
        e[(long)px * 16 + d] = f2bf(qv);
    }
    #pragma unroll
    for (int off = 32; off > 0; off >>= 1) lsum += __shfl_down(lsum, off, 64);
    if ((threadIdx.x & 63) == 0) atomicAdd(&acc[0], lsum);
}

// ---------------- dec1 MFMA: e -> d1 NHWC [B,128,128,64] --------------------
__global__ __launch_bounds__(256, 4) void dec1_k(const ushort_t* __restrict__ e,
        const ushort_t* __restrict__ wt, const float* __restrict__ bias,
        ushort_t* __restrict__ d1) {
    const int by = blockIdx.y, b = by >> 6, i = by & 63;
    const int tid = threadIdx.x;
    __shared__ __align__(16) ushort_t sE[2 * 66 * 24];  // [dh2][j66][ci16 pad24]
    uint4* z4 = (uint4*)sE;
    #pragma unroll
    for (int it = 0; it < 2; ++it) {
        int slot = it * 256 + tid;
        if (slot < 396) z4[slot] = (uint4){0, 0, 0, 0};
    }
    __syncthreads();
    {
        int dh = tid >> 7, rem = tid & 127, j = rem >> 1, ci8 = (rem & 1) * 8;
        if (i + dh < 64) {
            uint4 v = *(const uint4*)(e + ((long)((b * 64 + i + dh) * 64 + j)) * 16 + ci8);
            *(uint4*)&sE[(dh * 66 + j) * 24 + ci8] = v;
        }
    }
    __syncthreads();
    const int lane = tid & 63, wave = tid >> 6, q = lane >> 4, n16 = lane & 15;
    f32x4 acc[4][4];   // [class ph*2+pw][ntile]
    #pragma unroll
    for (int u = 0; u < 4; ++u) {
        float bz = bias[u * 16 + n16];
        #pragma unroll
        for (int c = 0; c < 4; ++c) acc[c][u] = (f32x4){bz, bz, bz, bz};
    }
    const int jl = wave * 16 + n16;
    #pragma unroll
    for (int t = 0; t < 9; ++t) {
        const int kh = t / 3, kw = t % 3;
        const int dh = (kh == 0) ? 1 : 0, dw = (kw == 0) ? 1 : 0;
        const int cls = ((kh != 1) ? 2 : 0) | ((kw != 1) ? 1 : 0);
        bf16x8 A = *(bf16x8*)&sE[(dh * 66 + jl + dw) * 24 + (q & 1) * 8];
        #pragma unroll
        for (int u = 0; u < 4; ++u) {
            bf16x8 B = *(const bf16x8*)(wt + 19456 + t * 2048 + (u * 16 + n16) * 32 + q * 8);
            acc[cls][u] = __builtin_amdgcn_mfma_f32_16x16x32_bf16(A, B, acc[cls][u], 0, 0, 0);
        }
    }
    #pragma unroll
    for (int ph = 0; ph < 2; ++ph)
        #pragma unroll
        for (int pw = 0; pw < 2; ++pw)
            #pragma unroll
            for (int u = 0; u < 4; ++u)
                #pragma unroll
                for (int r = 0; r < 4; ++r) {
                    int oh = 2 * i + ph;
                    int ow = 2 * (wave * 16 + q * 4 + r) + pw;
                    d1[((long)(b * 128 + oh) * 128 + ow) * 64 + u * 16 + n16] =
                        f2bf(fmaxf(acc[ph * 2 + pw][u][r], 0.f));
                }
}

// ---------------- dec2 MFMA: d1 -> d2 NHWC [B,256,256,32] -------------------
__global__ __launch_bounds__(256, 4) void dec2_k(const ushort_t* __restrict__ d1,
        const ushort_t* __restrict__ wt, const float* __restrict__ bias,
        ushort_t* __restrict__ d2) {
    const int by = blockIdx.y, b = by >> 7, i = by & 127;
    const int j0 = blockIdx.x * 64;
    const int tid = threadIdx.x;
    __shared__ __align__(16) ushort_t sD[2 * 66 * 72];  // [dh2][j66][ci64 pad72]
    uint4* z4 = (uint4*)sD;
    #pragma unroll
    for (int it = 0; it < 5; ++it) {
        int slot = it * 256 + tid;
        if (slot < 1188) z4[slot] = (uint4){0, 0, 0, 0};
    }
    __syncthreads();
    #pragma unroll
    for (int it = 0; it < 5; ++it) {
        int slot = it * 256 + tid;                    // 1040 = 2dh*65jj*8
        if (slot < 1040) {
            int dh = slot / 520, rem = slot % 520, jj = rem / 8, ci8 = (rem % 8) * 8;
            int j = j0 + jj;
            if (i + dh < 128 && j < 128) {
                uint4 v = *(const uint4*)(d1 + ((long)((b * 128 + i + dh) * 128 + j)) * 64 + ci8);
                *(uint4*)&sD[(dh * 66 + jj) * 72 + ci8] = v;
            }
        }
    }
    __syncthreads();
    const int lane = tid & 63, wave = tid >> 6, q = lane >> 4, n16 = lane & 15;
    f32x4 acc[4][2];
    #pragma unroll
    for (int u = 0; u < 2; ++u) {
        float bz = bias[u * 16 + n16];
        #pragma unroll
        for (int c = 0; c < 4; ++c) acc[c][u] = (f32x4){bz, bz, bz, bz};
    }
    const int jl = wave * 16 + n16;
    #pragma unroll
    for (int kc = 0; kc < 2; ++kc) {
        #pragma unroll
        for (int t = 0; t < 9; ++t) {
            const int kh = t / 3, kw = t % 3;
            const int dh = (kh == 0) ? 1 : 0, dw = (kw == 0) ? 1 : 0;
            const int cls = ((kh != 1) ? 2 : 0) | ((kw != 1) ? 1 : 0);
            bf16x8 A = *(bf16x8*)&sD[(dh * 66 + jl + dw) * 72 + kc * 32 + q * 8];
            #pragma unroll
            for (int u = 0; u < 2; ++u) {
                bf16x8 B = *(const bf16x8*)(wt + 37888 + t * 2048 + kc * 1024 +
                                            (u * 16 + n16) * 32 + q * 8);
                acc[cls][u] = __builtin_amdgcn_mfma_f32_16x16x32_bf16(A, B, acc[cls][u], 0, 0, 0);
            }
        }
    }
    #pragma unroll
    for (int ph = 0; ph < 2; ++ph)
        #pragma unroll
        for (int pw = 0; pw < 2; ++pw)
            #pragma unroll
            for (int u = 0; u < 2; ++u)
                #pragma unroll
                for (int r = 0; r < 4; ++r) {
                    int oh = 2 * i + ph;
                    int ow = 2 * (j0 + wave * 16 + q * 4 + r) + pw;
                    d2[((long)(b * 256 + oh) * 256 + ow) * 32 + u * 16 + n16] =
                        f2bf(fmaxf(acc[ph * 2 + pw][u][r], 0.f));
                }
}

// ---------------- dec3 (conv k3 p1, flipped W) + fused MSE ------------------
// One wave per output row; no LDS, no barriers. A-frags straight from global.
__global__ __launch_bounds__(256, 4) void dec3_mse_k(const ushort_t* __restrict__ d2,
        const ushort_t* __restrict__ wt, const float* __restrict__ bias,
        const float* __restrict__ x, float* __restrict__ acc) {
    const int by = blockIdx.y;               // C*64 blocks, 4 rows each
    const int b = by >> 6, row4 = by & 63;
    const int tid = threadIdx.x;
    const int lane = tid & 63, wave = tid >> 6, q = lane >> 4, n16 = lane & 15;
    const int oh = row4 * 4 + wave;
    bf16x8 Bw[9];
    #pragma unroll
    for (int t = 0; t < 9; ++t)
        Bw[t] = *(const bf16x8*)(wt + 56320 + t * 512 + n16 * 32 + q * 8);
    float bz = (n16 < 3) ? bias[n16] : 0.f;
    f32x4 a4[16];
    #pragma unroll
    for (int mf = 0; mf < 16; ++mf) a4[mf] = (f32x4){bz, bz, bz, bz};
    const ushort_t* dbase = d2 + (long)b * 2097152;   // 256*256*32
    #pragma unroll
    for (int kh = 0; kh < 3; ++kh) {
        int ih = oh + kh - 1;
        if ((unsigned)ih >= 256u) continue;          // wave-uniform
        const ushort_t* drow = dbase + (long)ih * 8192;
        #pragma unroll
        for (int kw = 0; kw < 3; ++kw) {
            #pragma unroll
            for (int mf = 0; mf < 16; ++mf) {
                int iw = mf * 16 + n16 + kw - 1;
                bool valid = (unsigned)iw < 256u;
                bf16x8 A = *(const bf16x8*)(drow + (valid ? iw : 0) * 32 + q * 8);
                if (!valid) A = (bf16x8){0, 0, 0, 0, 0, 0, 0, 0};
                a4[mf] = __builtin_amdgcn_mfma_f32_16x16x32_bf16(A, Bw[kh * 3 + kw], a4[mf], 0, 0, 0);
            }
        }
    }
    float lsum = 0.f;
    if (n16 < 3) {
        const float* xrow = x + ((long)(b * 3 + n16) * 256 + oh) * 256;
        #pragma unroll
        for (int mf = 0; mf < 16; ++mf)
            #pragma unroll
            for (int r = 0; r < 4; ++r) {
                int ow = mf * 16 + q * 4 + r;
                float df = a4[mf][r] - xrow[ow];
                lsum += df * df;
            }
    }
    #pragma unroll
    for (int off = 32; off > 0; off >>= 1) lsum += __shfl_down(lsum, off, 64);
    if (lane == 0) atomicAdd(&acc[1], lsum);
}

__global__ void finalize_k(const float* __restrict__ acc, float* __restrict__ out) {
    if (threadIdx.x == 0) {
        float eq  = 1.25f * acc[0] / 4194304.f;     // 262144 px * 16 d
        float mse = acc[1] / 12582912.f;            // 64 * 3 * 256 * 256
        out[0] = eq;
        out[1] = mse;
        out[2] = mse;
    }
}

extern "C" void kernel_launch(void* const* d_in, const int* in_sizes, int n_in,
                              void* d_out, int out_size, void* d_ws, size_t ws_size,
                              hipStream_t stream) {
    (void)in_sizes; (void)n_in; (void)out_size;
    const float* x   = (const float*)d_in[0];
    const float* ew1 = (const float*)d_in[1];
    const float* eb1 = (const float*)d_in[2];
    const float* ew2 = (const float*)d_in[3];
    const float* eb2 = (const float*)d_in[4];
    const float* ew3 = (const float*)d_in[5];
    const float* eb3 = (const float*)d_in[6];
    const float* cb  = (const float*)d_in[7];
    const float* dw1 = (const float*)d_in[8];
    const float* db1 = (const float*)d_in[9];
    const float* dw2 = (const float*)d_in[10];
    const float* db2 = (const float*)d_in[11];
    const float* dw3 = (const float*)d_in[12];
    const float* db3 = (const float*)d_in[13];
    float* out = (float*)d_out;

    // need(C) = 256(acc) + 131072(wbuf) + C*(131072 e + 6291456 region)
    int C = 64;
    while (C > 1 && (size_t)131328 + (size_t)C * 6422528UL > ws_size) C >>= 1;

    char* base = (char*)d_ws;
    float*    acc = (float*)base;
    ushort_t* wt  = (ushort_t*)(base + 256);
    float*    cn  = (float*)(base + 256 + 121856);
    ushort_t* e   = (ushort_t*)(base + 131328);
    char*     rgn = base + 131328 + (size_t)C * 131072UL;
    ushort_t* a1  = (ushort_t*)rgn;
    ushort_t* a2  = (ushort_t*)(rgn + (size_t)C * 1048576UL);
    ushort_t* dd1 = (ushort_t*)rgn;                          // reuse
    ushort_t* dd2 = (ushort_t*)(rgn + (size_t)C * 2097152UL);

    zero_k<<<1, 64, 0, stream>>>(acc);
    prep_k<<<240, 256, 0, stream>>>(ew1, ew2, dw1, dw2, dw3, cb, wt, cn);

    for (int b0 = 0; b0 < 64; b0 += C) {
        const float* xc = x + (size_t)b0 * 196608UL;
        conv1_k   <<<dim3(1, C * 128), 256, 0, stream>>>(xc,  wt, eb1, a1);
        conv2_k   <<<dim3(1, C * 64),  256, 0, stream>>>(a1,  wt, eb2, a2);
        conv3_vq_k<<<dim3(C * 16),     256, 0, stream>>>(a2,  ew3, eb3, cb, cn, e, acc);
        dec1_k    <<<dim3(1, C * 64),  256, 0, stream>>>(e,   wt, db1, dd1);
        dec2_k    <<<dim3(2, C * 128), 256, 0, stream>>>(dd1, wt, db2, dd2);
        dec3_mse_k<<<dim3(1, C * 64),  256, 0, stream>>>(dd2, wt, db3, xc, acc);
    }
    finalize_k<<<1, 64, 0, stream>>>(acc, out);
}

// Round 6
// 1070.466 us; speedup vs baseline: 11.4785x; 1.0601x over previous
//
#include <hip/hip_runtime.h>
#include <hip/hip_bf16.h>

// VQ-VAE forward — NHWC bf16 intermediates, MFMA (16x16x32 bf16) for all convs.
// Outputs: [1.25*vq_mse, recon_mse, recon_mse]
//
// MFMA lane layouts (gfx950, HW-verified per guide):
//   A: m = lane&15, k = (lane>>4)*8 + j     (8 bf16 / lane)
//   B: n = lane&15, k = (lane>>4)*8 + j
//   D: n = lane&15, m = (lane>>4)*4 + reg   (4 f32 / lane)
//
// Decoder buffers are PADDED so inner loops have zero conditionals:
//   d1p [B][129][129][64]  (interior (0,0)..(127,127); pad row 128, col 128 = 0)
//   d2p [B][258][258][32]  (interior offset (1,1); border rows/cols = 0)
// pad_k zeroes the borders each launch (ws is re-poisoned 0xAA).

typedef __attribute__((ext_vector_type(8))) short bf16x8;
typedef __attribute__((ext_vector_type(4))) float f32x4;
typedef unsigned short ushort_t;

__device__ __forceinline__ ushort_t f2bf(float v) {
    __hip_bfloat16 h = __float2bfloat16(v);
    return *(ushort_t*)&h;
}
__device__ __forceinline__ float bf2f(ushort_t u) {
    __hip_bfloat16 h = *(__hip_bfloat16*)&u;
    return __bfloat162float(h);
}

// Transformed-weight layout in wbuf (elements of bf16):
//   W1T  @ 0      [co32][k32]            (k=ci*9+kh*3+kw, pad 27->32)
//   W2T  @ 1024   [t9][co64][ci32]
//   WD1  @ 19456  [t9][co64][k32]        (k<16 = ci, else 0)
//   WD2  @ 37888  [t9][kc2][co32][ci32]
//   WD3  @ 56320  [t9][co16][ci32]       (taps FLIPPED: src 8-t; co>=3 -> 0)
//   cn (fp32, 512) @ byte offset 121856

__global__ void zero_k(float* __restrict__ acc) { acc[threadIdx.x] = 0.f; }

__global__ __launch_bounds__(256) void prep_k(
        const float* __restrict__ ew1, const float* __restrict__ ew2,
        const float* __restrict__ dw1, const float* __restrict__ dw2,
        const float* __restrict__ dw3, const float* __restrict__ cb,
        ushort_t* __restrict__ wt, float* __restrict__ cn) {
    int idx = blockIdx.x * 256 + threadIdx.x;
    if (idx < 1024) {
        int co = idx >> 5, k = idx & 31;
        wt[idx] = (k < 27) ? f2bf(ew1[co * 27 + k]) : (ushort_t)0;
    } else if (idx < 19456) {
        int i = idx - 1024;
        int t = i >> 11, co = (i >> 5) & 63, ci = i & 31;
        wt[idx] = f2bf(ew2[co * 288 + ci * 9 + t]);
    } else if (idx < 37888) {
        int i = idx - 19456;
        int t = i >> 11, co = (i >> 5) & 63, k = i & 31;
        wt[idx] = (k < 16) ? f2bf(dw1[k * 576 + co * 9 + t]) : (ushort_t)0;
    } else if (idx < 56320) {
        int i = idx - 37888;
        int t = i >> 11, kc = (i >> 10) & 1, co = (i >> 5) & 31, ci = i & 31;
        wt[idx] = f2bf(dw2[(kc * 32 + ci) * 288 + co * 9 + t]);
    } else if (idx < 60928) {
        int i = idx - 56320;
        int t = i >> 9, co = (i >> 5) & 15, ci = i & 31;
        wt[idx] = (co < 3) ? f2bf(dw3[ci * 27 + co * 9 + (8 - t)]) : (ushort_t)0;
    } else if (idx < 61440) {
        int k = idx - 60928;
        float s = 0.f;
        #pragma unroll
        for (int d = 0; d < 16; ++d) { float v = cb[k * 16 + d]; s += v * v; }
        cn[k] = s;
    }
}

// ---------------- zero the pad borders of d1p / d2p (one block per image) ---
__global__ __launch_bounds__(256) void pad_k(ushort_t* __restrict__ d1p,
                                             ushort_t* __restrict__ d2p) {
    const int img = blockIdx.x, tid = threadIdx.x;
    const uint4 z = (uint4){0, 0, 0, 0};
    uint4* b1 = (uint4*)(d1p + (size_t)img * 1065024);   // 129*129*64 elems
    // d1p row 128: contiguous 129*64 elems = 1032 uint4 at elem 128*129*64
    for (int i = tid; i < 1032; i += 256) b1[132096 + i] = z;
    // d1p col 128: rows 0..127, 64 elems = 8 uint4 each
    for (int i = tid; i < 1024; i += 256) {
        int r = i >> 3, u = i & 7;
        b1[(r * 129 + 128) * 8 + u] = z;
    }
    uint4* b2 = (uint4*)(d2p + (size_t)img * 2130048);   // 258*258*32 elems
    // d2p rows 0 and 257: 258*32 elems = 1032 uint4 each (row stride 1032 uint4)
    for (int i = tid; i < 1032; i += 256) { b2[i] = z; b2[257 * 1032 + i] = z; }
    // d2p cols 0 and 257: rows 1..256, 32 elems = 4 uint4 each
    for (int i = tid; i < 1024; i += 256) {
        int r = 1 + (i >> 2), u = i & 3;
        b2[(r * 258) * 4 + u] = z;
        b2[(r * 258 + 257) * 4 + u] = z;
    }
}

// ---------------- conv1 MFMA: x NCHW fp32 -> a1 NHWC bf16 [B,128,128,32] ----
__global__ __launch_bounds__(256, 4) void conv1_k(const float* __restrict__ x,
        const ushort_t* __restrict__ wt, const float* __restrict__ bias,
        ushort_t* __restrict__ a1) {
    const int by = blockIdx.y, b = by >> 7, oh = by & 127;
    const int tid = threadIdx.x;
    __shared__ __align__(16) ushort_t sX[9 * 264];   // [ci*3+kh][iw+1 (258 used)]
    __shared__ int sOff[32];
    for (int i = tid; i < 9 * 264 / 2; i += 256) ((unsigned*)sX)[i] = 0u;
    if (tid < 32) {
        int k = tid, off = 0;
        if (k < 27) { int ci = k / 9, r9 = k % 9, kh = r9 / 3, kw = r9 % 3;
                      off = (ci * 3 + kh) * 264 + kw; }
        sOff[tid] = off;
    }
    __syncthreads();
    #pragma unroll
    for (int it = 0; it < 9; ++it) {
        int slot = it * 256 + tid;                  // 2304 = 3ci * 3kh * 256iw
        int ci = slot / 768, r = slot % 768, kh = r >> 8, iw = r & 255;
        int ih = 2 * oh + kh - 1;
        float v = ((unsigned)ih < 256u) ? x[(long)(b * 3 + ci) * 65536 + ih * 256 + iw] : 0.f;
        sX[(ci * 3 + kh) * 264 + iw + 1] = f2bf(v);
    }
    __syncthreads();
    const int lane = tid & 63, wave = tid >> 6, q = lane >> 4, n16 = lane & 15;
    bf16x8 Bw[2];
    #pragma unroll
    for (int u = 0; u < 2; ++u)
        Bw[u] = *(const bf16x8*)(wt + (u * 16 + n16) * 32 + q * 8);
    f32x4 acc[2][2];
    #pragma unroll
    for (int u = 0; u < 2; ++u) {
        float bz = bias[u * 16 + n16];
        acc[0][u] = (f32x4){bz, bz, bz, bz};
        acc[1][u] = (f32x4){bz, bz, bz, bz};
    }
    #pragma unroll
    for (int mf = 0; mf < 2; ++mf) {
        const int m2 = 2 * (wave * 32 + mf * 16 + n16);
        ushort_t av[8];
        #pragma unroll
        for (int j = 0; j < 8; ++j) {
            int k = q * 8 + j;
            av[j] = (k < 27) ? sX[sOff[k] + m2] : (ushort_t)0;
        }
        bf16x8 A = *(bf16x8*)av;
        #pragma unroll
        for (int u = 0; u < 2; ++u)
            acc[mf][u] = __builtin_amdgcn_mfma_f32_16x16x32_bf16(A, Bw[u], acc[mf][u], 0, 0, 0);
    }
    #pragma unroll
    for (int mf = 0; mf < 2; ++mf)
        #pragma unroll
        for (int u = 0; u < 2; ++u)
            #pragma unroll
            for (int r = 0; r < 4; ++r) {
                int ow = wave * 32 + mf * 16 + q * 4 + r;
                a1[((long)(b * 128 + oh) * 128 + ow) * 32 + u * 16 + n16] =
                    f2bf(fmaxf(acc[mf][u][r], 0.f));
            }
}

// ---------------- conv2 MFMA: a1 -> a2 NHWC [B,64,64,64] --------------------
__global__ __launch_bounds__(256, 4) void conv2_k(const ushort_t* __restrict__ a1,
        const ushort_t* __restrict__ wt, const float* __restrict__ bias,
        ushort_t* __restrict__ a2) {
    const int by = blockIdx.y, b = by >> 6, oh = by & 63;
    const int tid = threadIdx.x;
    // parity-split: [kh3][p2][c66][ci32 pad40]
    __shared__ __align__(16) ushort_t sA[3 * 2 * 66 * 40];
    uint4* z4 = (uint4*)sA;
    #pragma unroll
    for (int it = 0; it < 8; ++it) {
        int slot = it * 256 + tid;
        if (slot < 1980) z4[slot] = (uint4){0, 0, 0, 0};
    }
    __syncthreads();
    #pragma unroll
    for (int it = 0; it < 6; ++it) {
        int slot = it * 256 + tid;                    // 1536 = 3kh*128iw*4
        if (slot < 1536) {
            int kh = slot >> 9, rem = slot & 511, iw = rem >> 2, ci8 = (rem & 3) << 3;
            int ih = 2 * oh + kh - 1;
            if ((unsigned)ih < 128u) {
                uint4 v = *(const uint4*)(a1 + ((long)(b * 128 + ih) * 128 + iw) * 32 + ci8);
                int idx = iw + 2, p = idx & 1, c = idx >> 1;
                *(uint4*)&sA[((kh * 2 + p) * 66 + c) * 40 + ci8] = v;
            }
        }
    }
    __syncthreads();
    const int lane = tid & 63, wave = tid >> 6, q = lane >> 4, n16 = lane & 15;
    f32x4 acc[4];
    #pragma unroll
    for (int u = 0; u < 4; ++u) {
        float bz = bias[u * 16 + n16];
        acc[u] = (f32x4){bz, bz, bz, bz};
    }
    const int ow = wave * 16 + n16;   // A row (m)
    #pragma unroll
    for (int t = 0; t < 9; ++t) {
        const int kh = t / 3, kw = t % 3;
        const int p = (kw == 1) ? 0 : 1;
        const int c = (kw == 0) ? ow : ow + 1;
        bf16x8 A = *(bf16x8*)&sA[((kh * 2 + p) * 66 + c) * 40 + q * 8];
        #pragma unroll
        for (int u = 0; u < 4; ++u) {
            bf16x8 B = *(const bf16x8*)(wt + 1024 + t * 2048 + (u * 16 + n16) * 32 + q * 8);
            acc[u] = __builtin_amdgcn_mfma_f32_16x16x32_bf16(A, B, acc[u], 0, 0, 0);
        }
    }
    #pragma unroll
    for (int u = 0; u < 4; ++u)
        #pragma unroll
        for (int r = 0; r < 4; ++r) {
            int owo = wave * 16 + q * 4 + r;
            a2[((long)(b * 64 + oh) * 64 + owo) * 64 + u * 16 + n16] =
                f2bf(fmaxf(acc[u][r], 0.f));
        }
}

// ---------------- conv3 (1x1) + VQ + loss: a2 -> e NHWC bf16 [B,64,64,16] ---
__global__ __launch_bounds__(256) void conv3_vq_k(const ushort_t* __restrict__ a2,
        const float* __restrict__ w3, const float* __restrict__ b3,
        const float* __restrict__ cb, const float* __restrict__ cn,
        ushort_t* __restrict__ e, float* __restrict__ acc) {
    const int px = blockIdx.x * 256 + threadIdx.x;
    const ushort_t* arow = a2 + (long)px * 64;
    float z[16];
    #pragma unroll
    for (int d = 0; d < 16; ++d) z[d] = b3[d];
    for (int c8 = 0; c8 < 8; ++c8) {
        uint4 raw = *(const uint4*)(arow + c8 * 8);
        ushort_t us[8];
        *(uint4*)us = raw;
        #pragma unroll
        for (int j = 0; j < 8; ++j) {
            float a = bf2f(us[j]);
            #pragma unroll
            for (int d = 0; d < 16; ++d)
                z[d] = fmaf(a, w3[d * 64 + c8 * 8 + j], z[d]);
        }
    }
    const float4* cb4 = (const float4*)cb;
    float best = 1e30f; int bi = 0;
    for (int k = 0; k < 512; ++k) {
        float4 c0 = cb4[k * 4 + 0], c1 = cb4[k * 4 + 1];
        float4 c2 = cb4[k * 4 + 2], c3 = cb4[k * 4 + 3];
        float d0 = z[0]*c0.x + z[1]*c0.y + z[2]*c0.z + z[3]*c0.w;
        float d1 = z[4]*c1.x + z[5]*c1.y + z[6]*c1.z + z[7]*c1.w;
        float d2 = z[8]*c2.x + z[9]*c2.y + z[10]*c2.z + z[11]*c2.w;
        float d3 = z[12]*c3.x + z[13]*c3.y + z[14]*c3.z + z[15]*c3.w;
        float dist = cn[k] - 2.f * (d0 + d1 + d2 + d3);
        if (dist < best) { best = dist; bi = k; }
    }
    float lsum = 0.f;
    #pragma unroll
    for (int d = 0; d < 16; ++d) {
        float qv = cb[bi * 16 + d];
        float df = qv - z[d];
        lsum += df * df;
        e[(long)px * 16 + d] = f2bf(qv);
    }
    #pragma unroll
    for (int off = 32; off > 0; off >>= 1) lsum += __shfl_down(lsum, off, 64);
    if ((threadIdx.x & 63) == 0) atomicAdd(&acc[0], lsum);
}

// ---------------- dec1 MFMA: e -> d1p (padded) [B,129,129,64] ---------------
__global__ __launch_bounds__(256, 4) void dec1_k(const ushort_t* __restrict__ e,
        const ushort_t* __restrict__ wt, const float* __restrict__ bias,
        ushort_t* __restrict__ d1p) {
    const int by = blockIdx.y, b = by >> 6, i = by & 63;
    const int tid = threadIdx.x;
    __shared__ __align__(16) ushort_t sE[2 * 66 * 24];  // [dh2][j66][ci16 pad24]
    uint4* z4 = (uint4*)sE;
    #pragma unroll
    for (int it = 0; it < 2; ++it) {
        int slot = it * 256 + tid;
        if (slot < 396) z4[slot] = (uint4){0, 0, 0, 0};
    }
    __syncthreads();
    {
        int dh = tid >> 7, rem = tid & 127, j = rem >> 1, ci8 = (rem & 1) * 8;
        if (i + dh < 64) {
            uint4 v = *(const uint4*)(e + ((long)((b * 64 + i + dh) * 64 + j)) * 16 + ci8);
            *(uint4*)&sE[(dh * 66 + j) * 24 + ci8] = v;
        }
    }
    __syncthreads();
    const int lane = tid & 63, wave = tid >> 6, q = lane >> 4, n16 = lane & 15;
    f32x4 acc[4][4];   // [class ph*2+pw][ntile]
    #pragma unroll
    for (int u = 0; u < 4; ++u) {
        float bz = bias[u * 16 + n16];
        #pragma unroll
        for (int c = 0; c < 4; ++c) acc[c][u] = (f32x4){bz, bz, bz, bz};
    }
    const int jl = wave * 16 + n16;
    #pragma unroll
    for (int t = 0; t < 9; ++t) {
        const int kh = t / 3, kw = t % 3;
        const int dh = (kh == 0) ? 1 : 0, dw = (kw == 0) ? 1 : 0;
        const int cls = ((kh != 1) ? 2 : 0) | ((kw != 1) ? 1 : 0);
        bf16x8 A = *(bf16x8*)&sE[(dh * 66 + jl + dw) * 24 + (q & 1) * 8];
        #pragma unroll
        for (int u = 0; u < 4; ++u) {
            bf16x8 B = *(const bf16x8*)(wt + 19456 + t * 2048 + (u * 16 + n16) * 32 + q * 8);
            acc[cls][u] = __builtin_amdgcn_mfma_f32_16x16x32_bf16(A, B, acc[cls][u], 0, 0, 0);
        }
    }
    #pragma unroll
    for (int ph = 0; ph < 2; ++ph)
        #pragma unroll
        for (int pw = 0; pw < 2; ++pw)
            #pragma unroll
            for (int u = 0; u < 4; ++u)
                #pragma unroll
                for (int r = 0; r < 4; ++r) {
                    int oh = 2 * i + ph;
                    int ow = 2 * (wave * 16 + q * 4 + r) + pw;
                    d1p[(size_t)b * 1065024 + ((long)oh * 129 + ow) * 64 + u * 16 + n16] =
                        f2bf(fmaxf(acc[ph * 2 + pw][u][r], 0.f));
                }
}

// ---------------- dec2 MFMA: d1p -> d2p (padded) [B,258,258,32] -------------
__global__ __launch_bounds__(256, 4) void dec2_k(const ushort_t* __restrict__ d1p,
        const ushort_t* __restrict__ wt, const float* __restrict__ bias,
        ushort_t* __restrict__ d2p) {
    const int by = blockIdx.y, b = by >> 7, i = by & 127;
    const int j0 = blockIdx.x * 64;
    const int tid = threadIdx.x;
    __shared__ __align__(16) ushort_t sD[2 * 66 * 72];  // [dh2][j66][ci64 pad72]
    #pragma unroll
    for (int it = 0; it < 5; ++it) {
        int slot = it * 256 + tid;                    // 1040 = 2dh*65jj*8
        if (slot < 1040) {
            int dh = slot / 520, rem = slot % 520, jj = rem / 8, ci8 = (rem % 8) * 8;
            int j = j0 + jj;                          // <= 128 (pad col)
            uint4 v = *(const uint4*)(d1p + (size_t)b * 1065024 +
                                      ((long)(i + dh) * 129 + j) * 64 + ci8);
            *(uint4*)&sD[(dh * 66 + jj) * 72 + ci8] = v;
        }
    }
    __syncthreads();
    const int lane = tid & 63, wave = tid >> 6, q = lane >> 4, n16 = lane & 15;
    f32x4 acc[4][2];
    #pragma unroll
    for (int u = 0; u < 2; ++u) {
        float bz = bias[u * 16 + n16];
        #pragma unroll
        for (int c = 0; c < 4; ++c) acc[c][u] = (f32x4){bz, bz, bz, bz};
    }
    const int jl = wave * 16 + n16;
    #pragma unroll
    for (int kc = 0; kc < 2; ++kc) {
        #pragma unroll
        for (int t = 0; t < 9; ++t) {
            const int kh = t / 3, kw = t % 3;
            const int dh = (kh == 0) ? 1 : 0, dw = (kw == 0) ? 1 : 0;
            const int cls = ((kh != 1) ? 2 : 0) | ((kw != 1) ? 1 : 0);
            bf16x8 A = *(bf16x8*)&sD[(dh * 66 + jl + dw) * 72 + kc * 32 + q * 8];
            #pragma unroll
            for (int u = 0; u < 2; ++u) {
                bf16x8 B = *(const bf16x8*)(wt + 37888 + t * 2048 + kc * 1024 +
                                            (u * 16 + n16) * 32 + q * 8);
                acc[cls][u] = __builtin_amdgcn_mfma_f32_16x16x32_bf16(A, B, acc[cls][u], 0, 0, 0);
            }
        }
    }
    #pragma unroll
    for (int ph = 0; ph < 2; ++ph)
        #pragma unroll
        for (int pw = 0; pw < 2; ++pw)
            #pragma unroll
            for (int u = 0; u < 2; ++u)
                #pragma unroll
                for (int r = 0; r < 4; ++r) {
                    int oh = 2 * i + ph;
                    int ow = 2 * (j0 + wave * 16 + q * 4 + r) + pw;
                    d2p[(size_t)b * 2130048 + ((long)(oh + 1) * 258 + ow + 1) * 32 + u * 16 + n16] =
                        f2bf(fmaxf(acc[ph * 2 + pw][u][r], 0.f));
                }
}

// ---------------- dec3 (conv k3 p1, flipped W) + fused MSE ------------------
// One wave per output row; no LDS/barriers; all loads unconditional (padded).
__global__ __launch_bounds__(256, 4) void dec3_mse_k(const ushort_t* __restrict__ d2p,
        const ushort_t* __restrict__ wt, const float* __restrict__ bias,
        const float* __restrict__ x, float* __restrict__ acc) {
    const int by = blockIdx.y;               // C*64 blocks, 4 rows each
    const int b = by >> 6, row4 = by & 63;
    const int tid = threadIdx.x;
    const int lane = tid & 63, wave = tid >> 6, q = lane >> 4, n16 = lane & 15;
    const int oh = row4 * 4 + wave;
    bf16x8 Bw[9];
    #pragma unroll
    for (int t = 0; t < 9; ++t)
        Bw[t] = *(const bf16x8*)(wt + 56320 + t * 512 + n16 * 32 + q * 8);
    float bz = (n16 < 3) ? bias[n16] : 0.f;
    f32x4 a4[16];
    #pragma unroll
    for (int mf = 0; mf < 16; ++mf) a4[mf] = (f32x4){bz, bz, bz, bz};
    const ushort_t* dbase = d2p + (size_t)b * 2130048;
    #pragma unroll
    for (int kh = 0; kh < 3; ++kh) {
        const ushort_t* drow = dbase + (long)(oh + kh) * 8256;   // 258*32
        #pragma unroll
        for (int mf = 0; mf < 16; ++mf) {
            #pragma unroll
            for (int kw = 0; kw < 3; ++kw) {
                bf16x8 A = *(const bf16x8*)(drow + (mf * 16 + n16 + kw) * 32 + q * 8);
                a4[mf] = __builtin_amdgcn_mfma_f32_16x16x32_bf16(A, Bw[kh * 3 + kw], a4[mf], 0, 0, 0);
            }
        }
    }
    float lsum = 0.f;
    if (n16 < 3) {
        const float* xrow = x + ((long)(b * 3 + n16) * 256 + oh) * 256;
        #pragma unroll
        for (int mf = 0; mf < 16; ++mf)
            #pragma unroll
            for (int r = 0; r < 4; ++r) {
                int ow = mf * 16 + q * 4 + r;
                float df = a4[mf][r] - xrow[ow];
                lsum += df * df;
            }
    }
    #pragma unroll
    for (int off = 32; off > 0; off >>= 1) lsum += __shfl_down(lsum, off, 64);
    if (lane == 0) atomicAdd(&acc[1], lsum);
}

__global__ void finalize_k(const float* __restrict__ acc, float* __restrict__ out) {
    if (threadIdx.x == 0) {
        float eq  = 1.25f * acc[0] / 4194304.f;     // 262144 px * 16 d
        float mse = acc[1] / 12582912.f;            // 64 * 3 * 256 * 256
        out[0] = eq;
        out[1] = mse;
        out[2] = mse;
    }
}

extern "C" void kernel_launch(void* const* d_in, const int* in_sizes, int n_in,
                              void* d_out, int out_size, void* d_ws, size_t ws_size,
                              hipStream_t stream) {
    (void)in_sizes; (void)n_in; (void)out_size;
    const float* x   = (const float*)d_in[0];
    const float* ew1 = (const float*)d_in[1];
    const float* eb1 = (const float*)d_in[2];
    const float* ew2 = (const float*)d_in[3];
    const float* eb2 = (const float*)d_in[4];
    const float* ew3 = (const float*)d_in[5];
    const float* eb3 = (const float*)d_in[6];
    const float* cb  = (const float*)d_in[7];
    const float* dw1 = (const float*)d_in[8];
    const float* db1 = (const float*)d_in[9];
    const float* dw2 = (const float*)d_in[10];
    const float* db2 = (const float*)d_in[11];
    const float* dw3 = (const float*)d_in[12];
    const float* db3 = (const float*)d_in[13];
    float* out = (float*)d_out;

    // per-image bytes: e 131072 | enc region a1 1048576 + a2 524288
    //                  dec region d1p 2130048 + d2p 4260096 = 6390144 (>= enc)
    // need(C) = 256(acc) + 131072(wbuf) + C*(131072 + 6390144)
    int C = 64;
    while (C > 1 && (size_t)131328 + (size_t)C * 6521216UL > ws_size) C >>= 1;

    char* base = (char*)d_ws;
    float*    acc = (float*)base;
    ushort_t* wt  = (ushort_t*)(base + 256);
    float*    cn  = (float*)(base + 256 + 121856);
    ushort_t* e   = (ushort_t*)(base + 131328);
    char*     rgn = base + 131328 + (size_t)C * 131072UL;
    ushort_t* a1  = (ushort_t*)rgn;
    ushort_t* a2  = (ushort_t*)(rgn + (size_t)C * 1048576UL);
    ushort_t* d1p = (ushort_t*)rgn;                          // reuse (a1/a2 dead)
    ushort_t* d2p = (ushort_t*)(rgn + (size_t)C * 2130048UL);

    zero_k<<<1, 64, 0, stream>>>(acc);
    prep_k<<<240, 256, 0, stream>>>(ew1, ew2, dw1, dw2, dw3, cb, wt, cn);

    for (int b0 = 0; b0 < 64; b0 += C) {
        const float* xc = x + (size_t)b0 * 196608UL;
        conv1_k   <<<dim3(1, C * 128), 256, 0, stream>>>(xc,  wt, eb1, a1);
        conv2_k   <<<dim3(1, C * 64),  256, 0, stream>>>(a1,  wt, eb2, a2);
        conv3_vq_k<<<dim3(C * 16),     256, 0, stream>>>(a2,  ew3, eb3, cb, cn, e, acc);
        pad_k     <<<dim3(C),          256, 0, stream>>>(d1p, d2p);
        dec1_k    <<<dim3(1, C * 64),  256, 0, stream>>>(e,   wt, db1, d1p);
        dec2_k    <<<dim3(2, C * 128), 256, 0, stream>>>(d1p, wt, db2, d2p);
        dec3_mse_k<<<dim3(1, C * 64),  256, 0, stream>>>(d2p, wt, db3, xc, acc);
    }
    finalize_k<<<1, 64, 0, stream>>>(acc, out);
}